// Round 1
// baseline (1564.035 us; speedup 1.0000x reference)
//
#include <hip/hip_runtime.h>
#include <math.h>

#define N_NODES 50000
#define T_STEPS 8
#define E_EDGES 800000
#define XD 128
#define HD 64
#define ZD 32
#define M_TOT (T_STEPS * N_NODES)   // 400000
#define TE_TOT (T_STEPS * E_EDGES)  // 6400000

#define SCAN_CH 2048
#define SCAN_NB ((M_TOT + SCAN_CH - 1) / SCAN_CH)  // 196

// ---------------- h0 = x @ W1  ([N,128] x [128,64]) ----------------
// 256 nodes/block, k-chunked (32) LDS tiling, 4 nodes x 16 j per thread.
__global__ __launch_bounds__(256) void k_h0(const float* __restrict__ x,
                                            const float* __restrict__ W1,
                                            float* __restrict__ h0) {
  __shared__ float xs[256 * 33];  // 256 nodes x 32 k, pad 33 (bank-conflict-free)
  __shared__ float w1s[32 * 64];  // k-chunk x 64 j
  const int tid = threadIdx.x;
  const int nb = blockIdx.x * 256;
  const int nl_base = tid & 63;  // node within wave
  const int jg = tid >> 6;       // 0..3 -> j = jg*16 .. +15
  const float4* x4 = (const float4*)x;
  const float4* W14 = (const float4*)W1;

  float acc[4][16];
#pragma unroll
  for (int i = 0; i < 4; ++i)
#pragma unroll
    for (int j = 0; j < 16; ++j) acc[i][j] = 0.f;

  for (int kc = 0; kc < 4; ++kc) {
    // stage x tile: 256 nodes x 32 k = 2048 float4
#pragma unroll
    for (int r = 0; r < 8; ++r) {
      int f4 = tid + r * 256;  // 0..2047
      int nl = f4 >> 3;
      int k4 = f4 & 7;
      float4 v = make_float4(0.f, 0.f, 0.f, 0.f);
      int node = nb + nl;
      if (node < N_NODES) v = x4[node * 32 + kc * 8 + k4];
      int base = nl * 33 + k4 * 4;
      xs[base + 0] = v.x; xs[base + 1] = v.y;
      xs[base + 2] = v.z; xs[base + 3] = v.w;
    }
    // stage W1 rows kc*32..+31 (all 64 j): 512 float4
#pragma unroll
    for (int r = 0; r < 2; ++r) {
      int f4 = tid + r * 256;
      ((float4*)w1s)[f4] = W14[kc * 512 + f4];
    }
    __syncthreads();
#pragma unroll 4
    for (int k = 0; k < 32; ++k) {
      float xv[4];
#pragma unroll
      for (int i = 0; i < 4; ++i) xv[i] = xs[(nl_base + i * 64) * 33 + k];
      const float* wr = &w1s[k * 64 + jg * 16];
      float4 w0 = *(const float4*)(wr + 0);
      float4 w1v = *(const float4*)(wr + 4);
      float4 w2v = *(const float4*)(wr + 8);
      float4 w3v = *(const float4*)(wr + 12);
#pragma unroll
      for (int i = 0; i < 4; ++i) {
        acc[i][0] += xv[i] * w0.x;  acc[i][1] += xv[i] * w0.y;
        acc[i][2] += xv[i] * w0.z;  acc[i][3] += xv[i] * w0.w;
        acc[i][4] += xv[i] * w1v.x; acc[i][5] += xv[i] * w1v.y;
        acc[i][6] += xv[i] * w1v.z; acc[i][7] += xv[i] * w1v.w;
        acc[i][8] += xv[i] * w2v.x; acc[i][9] += xv[i] * w2v.y;
        acc[i][10] += xv[i] * w2v.z; acc[i][11] += xv[i] * w2v.w;
        acc[i][12] += xv[i] * w3v.x; acc[i][13] += xv[i] * w3v.y;
        acc[i][14] += xv[i] * w3v.z; acc[i][15] += xv[i] * w3v.w;
      }
    }
    __syncthreads();
  }
  float4* h04 = (float4*)h0;
#pragma unroll
  for (int i = 0; i < 4; ++i) {
    int node = nb + nl_base + i * 64;
    if (node < N_NODES) {
#pragma unroll
      for (int q = 0; q < 4; ++q) {
        float4 v;
        v.x = acc[i][q * 4 + 0]; v.y = acc[i][q * 4 + 1];
        v.z = acc[i][q * 4 + 2]; v.w = acc[i][q * 4 + 3];
        h04[node * 16 + jg * 4 + q] = v;
      }
    }
  }
}

// ---------------- histogram: edge counts + weighted degree ----------------
__global__ __launch_bounds__(256) void k_hist(const int* __restrict__ ei,
                                              const float* __restrict__ ew,
                                              int* __restrict__ cnt,
                                              float* __restrict__ deg) {
  int i = blockIdx.x * 256 + threadIdx.x;  // < TE_TOT (exact grid)
  int t = i / E_EDGES;
  int e = i - t * E_EDGES;
  int dst = ei[(t * 2 + 1) * E_EDGES + e];
  float w = ew[i];  // ew[t*E+e] == ew[i]
  atomicAdd(&cnt[t * N_NODES + dst], 1);
  atomicAdd(&deg[t * N_NODES + dst], w);
}

// ---------------- dinv = rsqrt(1 + deg)  (self-loop weight 1) ----------------
__global__ __launch_bounds__(256) void k_dinv(const float* __restrict__ deg,
                                              float* __restrict__ dinv) {
  int i = blockIdx.x * 256 + threadIdx.x;
  if (i < M_TOT) dinv[i] = rsqrtf(1.0f + deg[i]);
}

// ---------------- hierarchical exclusive scan over cnt[M_TOT] ----------------
__global__ __launch_bounds__(256) void k_scan1(const int* __restrict__ cnt,
                                               int* __restrict__ bsum) {
  __shared__ int s[256];
  int bid = blockIdx.x, tid = threadIdx.x;
  int base = bid * SCAN_CH;
  int v = 0;
#pragma unroll
  for (int r = 0; r < 8; ++r) {
    int i = base + tid + r * 256;
    if (i < M_TOT) v += cnt[i];
  }
  s[tid] = v;
  __syncthreads();
  for (int off = 128; off > 0; off >>= 1) {
    if (tid < off) s[tid] += s[tid + off];
    __syncthreads();
  }
  if (tid == 0) bsum[bid] = s[0];
}

__global__ __launch_bounds__(256) void k_scan2(const int* __restrict__ bsum,
                                               int* __restrict__ bpre,
                                               int* __restrict__ row_off) {
  __shared__ int s[256];
  int tid = threadIdx.x;
  int v = (tid < SCAN_NB) ? bsum[tid] : 0;
  s[tid] = v;
  __syncthreads();
  for (int off = 1; off < 256; off <<= 1) {
    int t = (tid >= off) ? s[tid - off] : 0;
    __syncthreads();
    s[tid] += t;
    __syncthreads();
  }
  bpre[tid] = s[tid] - v;  // exclusive
  if (tid == 0) row_off[M_TOT] = TE_TOT;
}

__global__ __launch_bounds__(256) void k_scan3(const int* __restrict__ cnt,
                                               const int* __restrict__ bpre,
                                               int* __restrict__ row_off,
                                               int* __restrict__ cursor) {
  __shared__ int s[256];
  int bid = blockIdx.x, tid = threadIdx.x;
  int i0 = bid * SCAN_CH + tid * 8;
  int c[8];
  int lsum = 0;
#pragma unroll
  for (int j = 0; j < 8; ++j) {
    int i = i0 + j;
    c[j] = (i < M_TOT) ? cnt[i] : 0;
    lsum += c[j];
  }
  int v = lsum;
  s[tid] = v;
  __syncthreads();
  for (int off = 1; off < 256; off <<= 1) {
    int t = (tid >= off) ? s[tid - off] : 0;
    __syncthreads();
    s[tid] += t;
    __syncthreads();
  }
  int run = bpre[bid] + (s[tid] - v);
#pragma unroll
  for (int j = 0; j < 8; ++j) {
    int i = i0 + j;
    if (i < M_TOT) {
      row_off[i] = run;
      cursor[i] = run;
      run += c[j];
    }
  }
}

// ---------------- scatter edges into CSR (by dst, per t) ----------------
__global__ __launch_bounds__(256) void k_scatter(const int* __restrict__ ei,
                                                 const float* __restrict__ ew,
                                                 int* __restrict__ cursor,
                                                 int* __restrict__ csr_src,
                                                 float* __restrict__ csr_w) {
  int i = blockIdx.x * 256 + threadIdx.x;
  int t = i / E_EDGES;
  int e = i - t * E_EDGES;
  int src = ei[t * 2 * E_EDGES + e];
  int dst = ei[(t * 2 + 1) * E_EDGES + e];
  float w = ew[i];
  int p = atomicAdd(&cursor[t * N_NODES + dst], 1);
  csr_src[p] = src;
  csr_w[p] = w;
}

// ---------------- layer-1 gather + ReLU + fused h1@W2 ----------------
// block = 256 = 16 groups x 16 lanes; 16 nodes/block (N%16==0 so no t straddle issues)
__global__ __launch_bounds__(256) void k_gather1(
    const float* __restrict__ h0, const float* __restrict__ dinv,
    const int* __restrict__ row_off, const int* __restrict__ csr_src,
    const float* __restrict__ csr_w, const float* __restrict__ W2,
    const float* __restrict__ b1, float* __restrict__ g) {
  __shared__ float h1s[16 * 65];  // 16 nodes x 64, pad 65
  __shared__ float w2s[64 * 32];
  const int tid = threadIdx.x;
  // stage W2 (2048 floats)
#pragma unroll
  for (int r = 0; r < 2; ++r)
    ((float4*)w2s)[tid + r * 256] = ((const float4*)W2)[tid + r * 256];

  const int grp = tid >> 4;
  const int lane = tid & 15;  // feats lane*4..+3
  const int tn = blockIdx.x * 16 + grp;
  const int t = tn / N_NODES;
  const int tbase = t * N_NODES;
  const int n = tn - tbase;
  const float dvn = dinv[tn];
  const float4* h04 = (const float4*)h0;
  float4 bv = ((const float4*)b1)[lane];

  float4 acc = h04[n * 16 + lane];
  float sn = dvn * dvn;
  acc.x *= sn; acc.y *= sn; acc.z *= sn; acc.w *= sn;

  int e0 = row_off[tn], e1 = row_off[tn + 1];
  for (int e = e0; e < e1; ++e) {
    int src = csr_src[e];
    float w = csr_w[e];
    float norm = dinv[tbase + src] * w * dvn;
    float4 hv = h04[src * 16 + lane];
    acc.x += norm * hv.x; acc.y += norm * hv.y;
    acc.z += norm * hv.z; acc.w += norm * hv.w;
  }
  int hb = grp * 65 + lane * 4;
  h1s[hb + 0] = fmaxf(acc.x + bv.x, 0.f);
  h1s[hb + 1] = fmaxf(acc.y + bv.y, 0.f);
  h1s[hb + 2] = fmaxf(acc.z + bv.z, 0.f);
  h1s[hb + 3] = fmaxf(acc.w + bv.w, 0.f);
  __syncthreads();

  // block GEMM: g[16 nodes][32] = h1s @ W2; each thread 2 outputs
  const int n1 = tid >> 5;  // 0..7
  const int j = tid & 31;
  float a0 = 0.f, a1 = 0.f;
#pragma unroll 8
  for (int k = 0; k < 64; ++k) {
    float wv = w2s[k * 32 + j];
    a0 += h1s[n1 * 65 + k] * wv;
    a1 += h1s[(n1 + 8) * 65 + k] * wv;
  }
  const int tnb = blockIdx.x * 16;
  g[(size_t)(tnb + n1) * 32 + j] = a0;
  g[(size_t)(tnb + n1 + 8) * 32 + j] = a1;
}

// ---------------- layer-2 gather + bias + tanh -> out ----------------
// block = 256 = 32 groups x 8 lanes
__global__ __launch_bounds__(256) void k_gather2(
    const float* __restrict__ g, const float* __restrict__ dinv,
    const int* __restrict__ row_off, const int* __restrict__ csr_src,
    const float* __restrict__ csr_w, const float* __restrict__ b2,
    float* __restrict__ out) {
  const int tid = threadIdx.x;
  const int grp = tid >> 3;
  const int lane = tid & 7;  // feats lane*4..+3
  const int tn = blockIdx.x * 32 + grp;
  const int t = tn / N_NODES;
  const int tbase = t * N_NODES;
  const float dvn = dinv[tn];
  const float4* g4 = (const float4*)g;
  float4 bv = ((const float4*)b2)[lane];

  float4 acc = g4[(size_t)tn * 8 + lane];
  float sn = dvn * dvn;
  acc.x *= sn; acc.y *= sn; acc.z *= sn; acc.w *= sn;

  int e0 = row_off[tn], e1 = row_off[tn + 1];
  for (int e = e0; e < e1; ++e) {
    int src = csr_src[e];
    float w = csr_w[e];
    float norm = dinv[tbase + src] * w * dvn;
    float4 gv = g4[(size_t)(tbase + src) * 8 + lane];
    acc.x += norm * gv.x; acc.y += norm * gv.y;
    acc.z += norm * gv.z; acc.w += norm * gv.w;
  }
  float4 z;
  z.x = tanhf(acc.x + bv.x);
  z.y = tanhf(acc.y + bv.y);
  z.z = tanhf(acc.z + bv.z);
  z.w = tanhf(acc.w + bv.w);
  ((float4*)out)[(size_t)tn * 8 + lane] = z;
}

extern "C" void kernel_launch(void* const* d_in, const int* in_sizes, int n_in,
                              void* d_out, int out_size, void* d_ws, size_t ws_size,
                              hipStream_t stream) {
  const float* x = (const float*)d_in[0];
  const int* ei = (const int*)d_in[1];
  const float* ew = (const float*)d_in[2];
  const float* W1 = (const float*)d_in[3];
  const float* b1 = (const float*)d_in[4];
  const float* W2 = (const float*)d_in[5];
  const float* b2 = (const float*)d_in[6];
  float* out = (float*)d_out;

  char* base = (char*)d_ws;
  size_t o = 0;
  auto alloc = [&](size_t bytes) -> char* {
    char* r = base + o;
    o = (o + bytes + 255) & ~(size_t)255;
    return r;
  };
  float* h0 = (float*)alloc((size_t)N_NODES * HD * 4);   // 12.8 MB
  int* cnt = (int*)alloc((size_t)M_TOT * 4);             // 1.6 MB
  float* deg = (float*)alloc((size_t)M_TOT * 4);         // 1.6 MB (contiguous w/ cnt)
  float* dinv = (float*)alloc((size_t)M_TOT * 4);
  int* row_off = (int*)alloc((size_t)(M_TOT + 1) * 4);
  int* cursor = (int*)alloc((size_t)M_TOT * 4);
  int* bsum = (int*)alloc(1024);
  int* bpre = (int*)alloc(1024);
  int* csr_src = (int*)alloc((size_t)TE_TOT * 4);        // 25.6 MB
  float* csr_w = (float*)alloc((size_t)TE_TOT * 4);      // 25.6 MB
  float* g = (float*)alloc((size_t)M_TOT * ZD * 4);      // 51.2 MB
  // total ~123.3 MB

  // zero cnt + deg in one shot (they are contiguous, both 256B-multiples)
  hipMemsetAsync(cnt, 0, (size_t)M_TOT * 4 * 2, stream);

  k_h0<<<(N_NODES + 255) / 256, 256, 0, stream>>>(x, W1, h0);
  k_hist<<<TE_TOT / 256, 256, 0, stream>>>(ei, ew, cnt, deg);
  k_dinv<<<(M_TOT + 255) / 256, 256, 0, stream>>>(deg, dinv);
  k_scan1<<<SCAN_NB, 256, 0, stream>>>(cnt, bsum);
  k_scan2<<<1, 256, 0, stream>>>(bsum, bpre, row_off);
  k_scan3<<<SCAN_NB, 256, 0, stream>>>(cnt, bpre, row_off, cursor);
  k_scatter<<<TE_TOT / 256, 256, 0, stream>>>(ei, ew, cursor, csr_src, csr_w);
  k_gather1<<<M_TOT / 16, 256, 0, stream>>>(h0, dinv, row_off, csr_src, csr_w, W2, b1, g);
  k_gather2<<<M_TOT / 32, 256, 0, stream>>>(g, dinv, row_off, csr_src, csr_w, b2, out);
}

// Round 2
// 981.696 us; speedup vs baseline: 1.5932x; 1.5932x over previous
//
#include <hip/hip_runtime.h>
#include <math.h>

#define N_NODES 50000
#define T_STEPS 8
#define E_EDGES 800000
#define XD 128
#define HD 64
#define ZD 32
#define M_TOT (T_STEPS * N_NODES)   // 400000
#define TE_TOT (T_STEPS * E_EDGES)  // 6400000

#define SCAN_CH 2048
#define SCAN_NB ((M_TOT + SCAN_CH - 1) / SCAN_CH)  // 196

#define DEG_SCALE 1048576.0f      // 2^20 fixed point for weighted degree
#define DEG_INV_SCALE 9.5367431640625e-7f

// ---------------- h0 = x @ W1  ([N,128] x [128,64]) ----------------
__global__ __launch_bounds__(256) void k_h0(const float* __restrict__ x,
                                            const float* __restrict__ W1,
                                            float* __restrict__ h0) {
  __shared__ float xs[256 * 33];
  __shared__ float w1s[32 * 64];
  const int tid = threadIdx.x;
  const int nb = blockIdx.x * 256;
  const int nl_base = tid & 63;
  const int jg = tid >> 6;
  const float4* x4 = (const float4*)x;
  const float4* W14 = (const float4*)W1;

  float acc[4][16];
#pragma unroll
  for (int i = 0; i < 4; ++i)
#pragma unroll
    for (int j = 0; j < 16; ++j) acc[i][j] = 0.f;

  for (int kc = 0; kc < 4; ++kc) {
#pragma unroll
    for (int r = 0; r < 8; ++r) {
      int f4 = tid + r * 256;
      int nl = f4 >> 3;
      int k4 = f4 & 7;
      float4 v = make_float4(0.f, 0.f, 0.f, 0.f);
      int node = nb + nl;
      if (node < N_NODES) v = x4[node * 32 + kc * 8 + k4];
      int base = nl * 33 + k4 * 4;
      xs[base + 0] = v.x; xs[base + 1] = v.y;
      xs[base + 2] = v.z; xs[base + 3] = v.w;
    }
#pragma unroll
    for (int r = 0; r < 2; ++r) {
      int f4 = tid + r * 256;
      ((float4*)w1s)[f4] = W14[kc * 512 + f4];
    }
    __syncthreads();
#pragma unroll 4
    for (int k = 0; k < 32; ++k) {
      float xv[4];
#pragma unroll
      for (int i = 0; i < 4; ++i) xv[i] = xs[(nl_base + i * 64) * 33 + k];
      const float* wr = &w1s[k * 64 + jg * 16];
      float4 w0 = *(const float4*)(wr + 0);
      float4 w1v = *(const float4*)(wr + 4);
      float4 w2v = *(const float4*)(wr + 8);
      float4 w3v = *(const float4*)(wr + 12);
#pragma unroll
      for (int i = 0; i < 4; ++i) {
        acc[i][0] += xv[i] * w0.x;  acc[i][1] += xv[i] * w0.y;
        acc[i][2] += xv[i] * w0.z;  acc[i][3] += xv[i] * w0.w;
        acc[i][4] += xv[i] * w1v.x; acc[i][5] += xv[i] * w1v.y;
        acc[i][6] += xv[i] * w1v.z; acc[i][7] += xv[i] * w1v.w;
        acc[i][8] += xv[i] * w2v.x; acc[i][9] += xv[i] * w2v.y;
        acc[i][10] += xv[i] * w2v.z; acc[i][11] += xv[i] * w2v.w;
        acc[i][12] += xv[i] * w3v.x; acc[i][13] += xv[i] * w3v.y;
        acc[i][14] += xv[i] * w3v.z; acc[i][15] += xv[i] * w3v.w;
      }
    }
    __syncthreads();
  }
  float4* h04 = (float4*)h0;
#pragma unroll
  for (int i = 0; i < 4; ++i) {
    int node = nb + nl_base + i * 64;
    if (node < N_NODES) {
#pragma unroll
      for (int q = 0; q < 4; ++q) {
        float4 v;
        v.x = acc[i][q * 4 + 0]; v.y = acc[i][q * 4 + 1];
        v.z = acc[i][q * 4 + 2]; v.w = acc[i][q * 4 + 3];
        h04[node * 16 + jg * 4 + q] = v;
      }
    }
  }
}

// ---------------- fused histogram: ONE u64 atomic = (cnt | deg_fixed) ----------
// Returned old value's hi-32 = this edge's rank among same-dst edges.
__global__ __launch_bounds__(256) void k_hist(const int* __restrict__ ei,
                                              const float* __restrict__ ew,
                                              unsigned long long* __restrict__ packed,
                                              unsigned short* __restrict__ rank) {
  int i = blockIdx.x * 256 + threadIdx.x;  // exact grid == TE_TOT
  int t = i / E_EDGES;
  int e = i - t * E_EDGES;
  int dst = ei[(t * 2 + 1) * E_EDGES + e];
  float w = ew[i];
  unsigned long long inc =
      (1ull << 32) | (unsigned long long)(unsigned int)__float2uint_rn(w * DEG_SCALE);
  unsigned long long old = atomicAdd(&packed[t * N_NODES + dst], inc);
  rank[i] = (unsigned short)(old >> 32);
}

// ---------------- dinv = rsqrt(1 + deg) ----------------
__global__ __launch_bounds__(256) void k_dinv(const unsigned long long* __restrict__ packed,
                                              float* __restrict__ dinv) {
  int i = blockIdx.x * 256 + threadIdx.x;
  if (i < M_TOT) {
    float deg = (float)(unsigned int)(packed[i] & 0xffffffffull) * DEG_INV_SCALE;
    dinv[i] = rsqrtf(1.0f + deg);
  }
}

// ---------------- hierarchical exclusive scan over counts ----------------
__global__ __launch_bounds__(256) void k_scan1(const unsigned long long* __restrict__ packed,
                                               int* __restrict__ bsum) {
  __shared__ int s[256];
  int bid = blockIdx.x, tid = threadIdx.x;
  int base = bid * SCAN_CH;
  int v = 0;
#pragma unroll
  for (int r = 0; r < 8; ++r) {
    int i = base + tid + r * 256;
    if (i < M_TOT) v += (int)(packed[i] >> 32);
  }
  s[tid] = v;
  __syncthreads();
  for (int off = 128; off > 0; off >>= 1) {
    if (tid < off) s[tid] += s[tid + off];
    __syncthreads();
  }
  if (tid == 0) bsum[bid] = s[0];
}

__global__ __launch_bounds__(256) void k_scan2(const int* __restrict__ bsum,
                                               int* __restrict__ bpre,
                                               int* __restrict__ row_off) {
  __shared__ int s[256];
  int tid = threadIdx.x;
  int v = (tid < SCAN_NB) ? bsum[tid] : 0;
  s[tid] = v;
  __syncthreads();
  for (int off = 1; off < 256; off <<= 1) {
    int t = (tid >= off) ? s[tid - off] : 0;
    __syncthreads();
    s[tid] += t;
    __syncthreads();
  }
  bpre[tid] = s[tid] - v;
  if (tid == 0) row_off[M_TOT] = TE_TOT;
}

__global__ __launch_bounds__(256) void k_scan3(const unsigned long long* __restrict__ packed,
                                               const int* __restrict__ bpre,
                                               int* __restrict__ row_off) {
  __shared__ int s[256];
  int bid = blockIdx.x, tid = threadIdx.x;
  int i0 = bid * SCAN_CH + tid * 8;
  int c[8];
  int lsum = 0;
#pragma unroll
  for (int j = 0; j < 8; ++j) {
    int i = i0 + j;
    c[j] = (i < M_TOT) ? (int)(packed[i] >> 32) : 0;
    lsum += c[j];
  }
  int v = lsum;
  s[tid] = v;
  __syncthreads();
  for (int off = 1; off < 256; off <<= 1) {
    int t = (tid >= off) ? s[tid - off] : 0;
    __syncthreads();
    s[tid] += t;
    __syncthreads();
  }
  int run = bpre[bid] + (s[tid] - v);
#pragma unroll
  for (int j = 0; j < 8; ++j) {
    int i = i0 + j;
    if (i < M_TOT) {
      row_off[i] = run;
      run += c[j];
    }
  }
}

// ---------------- scatter edges into CSR: NO atomics ----------------
// Pre-scales weight by dinv[src]*dinv[dst] so gathers need no dinv loads.
__global__ __launch_bounds__(256) void k_scatter(const int* __restrict__ ei,
                                                 const float* __restrict__ ew,
                                                 const unsigned short* __restrict__ rank,
                                                 const int* __restrict__ row_off,
                                                 const float* __restrict__ dinv,
                                                 uint2* __restrict__ csr) {
  int i = blockIdx.x * 256 + threadIdx.x;
  int t = i / E_EDGES;
  int e = i - t * E_EDGES;
  int src = ei[t * 2 * E_EDGES + e];
  int dst = ei[(t * 2 + 1) * E_EDGES + e];
  float w = ew[i];
  int tb = t * N_NODES;
  float norm = dinv[tb + src] * w * dinv[tb + dst];
  int p = row_off[tb + dst] + (int)rank[i];
  csr[p] = make_uint2((unsigned int)src, __float_as_uint(norm));
}

// ---------------- layer-1 gather + ReLU + fused h1@W2 ----------------
__global__ __launch_bounds__(256) void k_gather1(
    const float* __restrict__ h0, const float* __restrict__ dinv,
    const int* __restrict__ row_off, const uint2* __restrict__ csr,
    const float* __restrict__ W2, const float* __restrict__ b1,
    float* __restrict__ g) {
  __shared__ float h1s[16 * 65];
  __shared__ float w2s[64 * 32];
  const int tid = threadIdx.x;
#pragma unroll
  for (int r = 0; r < 2; ++r)
    ((float4*)w2s)[tid + r * 256] = ((const float4*)W2)[tid + r * 256];

  const int grp = tid >> 4;
  const int lane = tid & 15;
  const int tn = blockIdx.x * 16 + grp;
  const int t = tn / N_NODES;
  const int n = tn - t * N_NODES;
  const float dvn = dinv[tn];
  const float4* h04 = (const float4*)h0;
  float4 bv = ((const float4*)b1)[lane];

  float4 acc = h04[n * 16 + lane];
  float sn = dvn * dvn;
  acc.x *= sn; acc.y *= sn; acc.z *= sn; acc.w *= sn;

  int e0 = row_off[tn], e1 = row_off[tn + 1];
  for (int e = e0; e < e1; ++e) {
    uint2 v = csr[e];
    float norm = __uint_as_float(v.y);
    float4 hv = h04[v.x * 16 + lane];
    acc.x += norm * hv.x; acc.y += norm * hv.y;
    acc.z += norm * hv.z; acc.w += norm * hv.w;
  }
  int hb = grp * 65 + lane * 4;
  h1s[hb + 0] = fmaxf(acc.x + bv.x, 0.f);
  h1s[hb + 1] = fmaxf(acc.y + bv.y, 0.f);
  h1s[hb + 2] = fmaxf(acc.z + bv.z, 0.f);
  h1s[hb + 3] = fmaxf(acc.w + bv.w, 0.f);
  __syncthreads();

  const int n1 = tid >> 5;
  const int j = tid & 31;
  float a0 = 0.f, a1 = 0.f;
#pragma unroll 8
  for (int k = 0; k < 64; ++k) {
    float wv = w2s[k * 32 + j];
    a0 += h1s[n1 * 65 + k] * wv;
    a1 += h1s[(n1 + 8) * 65 + k] * wv;
  }
  const int tnb = blockIdx.x * 16;
  g[(size_t)(tnb + n1) * 32 + j] = a0;
  g[(size_t)(tnb + n1 + 8) * 32 + j] = a1;
}

// ---------------- layer-2 gather + bias + tanh -> out ----------------
__global__ __launch_bounds__(256) void k_gather2(
    const float* __restrict__ g, const float* __restrict__ dinv,
    const int* __restrict__ row_off, const uint2* __restrict__ csr,
    const float* __restrict__ b2, float* __restrict__ out) {
  const int tid = threadIdx.x;
  const int grp = tid >> 3;
  const int lane = tid & 7;
  const int tn = blockIdx.x * 32 + grp;
  const int t = tn / N_NODES;
  const int tbase = t * N_NODES;
  const float dvn = dinv[tn];
  const float4* g4 = (const float4*)g;
  float4 bv = ((const float4*)b2)[lane];

  float4 acc = g4[(size_t)tn * 8 + lane];
  float sn = dvn * dvn;
  acc.x *= sn; acc.y *= sn; acc.z *= sn; acc.w *= sn;

  int e0 = row_off[tn], e1 = row_off[tn + 1];
  for (int e = e0; e < e1; ++e) {
    uint2 v = csr[e];
    float norm = __uint_as_float(v.y);
    float4 gv = g4[(size_t)(tbase + (int)v.x) * 8 + lane];
    acc.x += norm * gv.x; acc.y += norm * gv.y;
    acc.z += norm * gv.z; acc.w += norm * gv.w;
  }
  float4 z;
  z.x = tanhf(acc.x + bv.x);
  z.y = tanhf(acc.y + bv.y);
  z.z = tanhf(acc.z + bv.z);
  z.w = tanhf(acc.w + bv.w);
  ((float4*)out)[(size_t)tn * 8 + lane] = z;
}

extern "C" void kernel_launch(void* const* d_in, const int* in_sizes, int n_in,
                              void* d_out, int out_size, void* d_ws, size_t ws_size,
                              hipStream_t stream) {
  const float* x = (const float*)d_in[0];
  const int* ei = (const int*)d_in[1];
  const float* ew = (const float*)d_in[2];
  const float* W1 = (const float*)d_in[3];
  const float* b1 = (const float*)d_in[4];
  const float* W2 = (const float*)d_in[5];
  const float* b2 = (const float*)d_in[6];
  float* out = (float*)d_out;

  char* base = (char*)d_ws;
  size_t o = 0;
  auto alloc = [&](size_t bytes) -> char* {
    char* r = base + o;
    o = (o + bytes + 255) & ~(size_t)255;
    return r;
  };
  float* h0 = (float*)alloc((size_t)N_NODES * HD * 4);            // 12.8 MB
  unsigned long long* packed = (unsigned long long*)alloc((size_t)M_TOT * 8);  // 3.2 MB
  float* dinv = (float*)alloc((size_t)M_TOT * 4);                 // 1.6 MB
  int* row_off = (int*)alloc((size_t)(M_TOT + 1) * 4);            // 1.6 MB
  int* bsum = (int*)alloc(1024);
  int* bpre = (int*)alloc(1024);
  uint2* csr = (uint2*)alloc((size_t)TE_TOT * 8);                 // 51.2 MB
  float* g = (float*)alloc((size_t)M_TOT * ZD * 4);               // 51.2 MB
  // rank aliases the start of g: consumed by k_scatter BEFORE k_gather1 writes g
  unsigned short* rank = (unsigned short*)g;                      // 12.8 MB
  // total ~121.8 MB

  hipMemsetAsync(packed, 0, (size_t)M_TOT * 8, stream);

  k_h0<<<(N_NODES + 255) / 256, 256, 0, stream>>>(x, W1, h0);
  k_hist<<<TE_TOT / 256, 256, 0, stream>>>(ei, ew, packed, rank);
  k_dinv<<<(M_TOT + 255) / 256, 256, 0, stream>>>(packed, dinv);
  k_scan1<<<SCAN_NB, 256, 0, stream>>>(packed, bsum);
  k_scan2<<<1, 256, 0, stream>>>(bsum, bpre, row_off);
  k_scan3<<<SCAN_NB, 256, 0, stream>>>(packed, bpre, row_off);
  k_scatter<<<TE_TOT / 256, 256, 0, stream>>>(ei, ew, rank, row_off, dinv, csr);
  k_gather1<<<M_TOT / 16, 256, 0, stream>>>(h0, dinv, row_off, csr, W2, b1, g);
  k_gather2<<<M_TOT / 32, 256, 0, stream>>>(g, dinv, row_off, csr, b2, out);
}

// Round 3
// 788.014 us; speedup vs baseline: 1.9848x; 1.2458x over previous
//
#include <hip/hip_runtime.h>
#include <math.h>

#define N_NODES 50000
#define T_STEPS 8
#define E_EDGES 800000
#define XD 128
#define HD 64
#define ZD 32
#define M_TOT (T_STEPS * N_NODES)   // 400000
#define TE_TOT (T_STEPS * E_EDGES)  // 6400000

#define NBKT 196                    // ceil(50000/256) buckets of 256 dst values
#define BPT 125                     // pass-A blocks per timestep
#define EPB 6400                    // edges per pass-A block (125*6400 = 800000)
#define NBLK_A (T_STEPS * BPT)      // 1000
#define CNTA_LEN (T_STEPS * NBKT * BPT)  // 196000
#define NBUCK_T (T_STEPS * NBKT)    // 1568
#define BKT_CAP 4864                // mean 4096 + 12 sigma — statistically certain

#define SCAN_CH 2048
#define SCANA_NB ((CNTA_LEN + SCAN_CH - 1) / SCAN_CH)  // 96

// ---------------- h0 = x @ W1  ([N,128] x [128,64]) ----------------
__global__ __launch_bounds__(256) void k_h0(const float* __restrict__ x,
                                            const float* __restrict__ W1,
                                            float* __restrict__ h0) {
  __shared__ float xs[256 * 33];
  __shared__ float w1s[32 * 64];
  const int tid = threadIdx.x;
  const int nb = blockIdx.x * 256;
  const int nl_base = tid & 63;
  const int jg = tid >> 6;
  const float4* x4 = (const float4*)x;
  const float4* W14 = (const float4*)W1;

  float acc[4][16];
#pragma unroll
  for (int i = 0; i < 4; ++i)
#pragma unroll
    for (int j = 0; j < 16; ++j) acc[i][j] = 0.f;

  for (int kc = 0; kc < 4; ++kc) {
#pragma unroll
    for (int r = 0; r < 8; ++r) {
      int f4 = tid + r * 256;
      int nl = f4 >> 3;
      int k4 = f4 & 7;
      float4 v = make_float4(0.f, 0.f, 0.f, 0.f);
      int node = nb + nl;
      if (node < N_NODES) v = x4[node * 32 + kc * 8 + k4];
      int base = nl * 33 + k4 * 4;
      xs[base + 0] = v.x; xs[base + 1] = v.y;
      xs[base + 2] = v.z; xs[base + 3] = v.w;
    }
#pragma unroll
    for (int r = 0; r < 2; ++r) {
      int f4 = tid + r * 256;
      ((float4*)w1s)[f4] = W14[kc * 512 + f4];
    }
    __syncthreads();
#pragma unroll 4
    for (int k = 0; k < 32; ++k) {
      float xv[4];
#pragma unroll
      for (int i = 0; i < 4; ++i) xv[i] = xs[(nl_base + i * 64) * 33 + k];
      const float* wr = &w1s[k * 64 + jg * 16];
      float4 w0 = *(const float4*)(wr + 0);
      float4 w1v = *(const float4*)(wr + 4);
      float4 w2v = *(const float4*)(wr + 8);
      float4 w3v = *(const float4*)(wr + 12);
#pragma unroll
      for (int i = 0; i < 4; ++i) {
        acc[i][0] += xv[i] * w0.x;  acc[i][1] += xv[i] * w0.y;
        acc[i][2] += xv[i] * w0.z;  acc[i][3] += xv[i] * w0.w;
        acc[i][4] += xv[i] * w1v.x; acc[i][5] += xv[i] * w1v.y;
        acc[i][6] += xv[i] * w1v.z; acc[i][7] += xv[i] * w1v.w;
        acc[i][8] += xv[i] * w2v.x; acc[i][9] += xv[i] * w2v.y;
        acc[i][10] += xv[i] * w2v.z; acc[i][11] += xv[i] * w2v.w;
        acc[i][12] += xv[i] * w3v.x; acc[i][13] += xv[i] * w3v.y;
        acc[i][14] += xv[i] * w3v.z; acc[i][15] += xv[i] * w3v.w;
      }
    }
    __syncthreads();
  }
  float4* h04 = (float4*)h0;
#pragma unroll
  for (int i = 0; i < 4; ++i) {
    int node = nb + nl_base + i * 64;
    if (node < N_NODES) {
#pragma unroll
      for (int q = 0; q < 4; ++q) {
        float4 v;
        v.x = acc[i][q * 4 + 0]; v.y = acc[i][q * 4 + 1];
        v.z = acc[i][q * 4 + 2]; v.w = acc[i][q * 4 + 3];
        h04[node * 16 + jg * 4 + q] = v;
      }
    }
  }
}

// ---------------- pass A: per-block LDS histogram over dst>>8 ----------------
// LDS atomic return = edge's rank within (block,bucket). No global atomics.
__global__ __launch_bounds__(256) void k_binhist(const int* __restrict__ ei,
                                                 unsigned short* __restrict__ rankA,
                                                 unsigned int* __restrict__ cntA) {
  __shared__ unsigned int hist[NBKT];
  const int tid = threadIdx.x, bid = blockIdx.x;
  const int t = bid / BPT, b = bid - t * BPT;
  if (tid < NBKT) hist[tid] = 0;
  __syncthreads();
  const int* dstp = ei + (t * 2 + 1) * E_EDGES + b * EPB;
  const int gbase = t * E_EDGES + b * EPB;
#pragma unroll
  for (int it = 0; it < EPB / 256; ++it) {
    int e = it * 256 + tid;
    int dst = dstp[e];
    unsigned int r = atomicAdd(&hist[dst >> 8], 1u);
    rankA[gbase + e] = (unsigned short)r;
  }
  __syncthreads();
  if (tid < NBKT) cntA[(t * NBKT + tid) * BPT + b] = hist[tid];
}

// ---------------- hierarchical exclusive scan over cntA[CNTA_LEN] ----------------
__global__ __launch_bounds__(256) void k_scan1(const unsigned int* __restrict__ cntA,
                                               int* __restrict__ bsum) {
  __shared__ int s[256];
  int bid = blockIdx.x, tid = threadIdx.x;
  int base = bid * SCAN_CH;
  int v = 0;
#pragma unroll
  for (int r = 0; r < 8; ++r) {
    int i = base + tid + r * 256;
    if (i < CNTA_LEN) v += (int)cntA[i];
  }
  s[tid] = v;
  __syncthreads();
  for (int off = 128; off > 0; off >>= 1) {
    if (tid < off) s[tid] += s[tid + off];
    __syncthreads();
  }
  if (tid == 0) bsum[bid] = s[0];
}

__global__ __launch_bounds__(256) void k_scan2(const int* __restrict__ bsum,
                                               int* __restrict__ bpre) {
  __shared__ int s[256];
  int tid = threadIdx.x;
  int v = (tid < SCANA_NB) ? bsum[tid] : 0;
  s[tid] = v;
  __syncthreads();
  for (int off = 1; off < 256; off <<= 1) {
    int t = (tid >= off) ? s[tid - off] : 0;
    __syncthreads();
    s[tid] += t;
    __syncthreads();
  }
  bpre[tid] = s[tid] - v;
}

__global__ __launch_bounds__(256) void k_scan3(const unsigned int* __restrict__ cntA,
                                               const int* __restrict__ bpre,
                                               unsigned int* __restrict__ scannedA) {
  __shared__ int s[256];
  int bid = blockIdx.x, tid = threadIdx.x;
  int i0 = bid * SCAN_CH + tid * 8;
  int c[8];
  int lsum = 0;
#pragma unroll
  for (int j = 0; j < 8; ++j) {
    int i = i0 + j;
    c[j] = (i < CNTA_LEN) ? (int)cntA[i] : 0;
    lsum += c[j];
  }
  int v = lsum;
  s[tid] = v;
  __syncthreads();
  for (int off = 1; off < 256; off <<= 1) {
    int t = (tid >= off) ? s[tid - off] : 0;
    __syncthreads();
    s[tid] += t;
    __syncthreads();
  }
  int run = bpre[bid] + (s[tid] - v);
#pragma unroll
  for (int j = 0; j < 8; ++j) {
    int i = i0 + j;
    if (i < CNTA_LEN) {
      scannedA[i] = (unsigned int)run;
      run += c[j];
    }
  }
}

// ---------------- pass A scatter into bucket-grouped buffer: NO atomics ----------
__global__ __launch_bounds__(256) void k_binscatter(const int* __restrict__ ei,
                                                    const float* __restrict__ ew,
                                                    const unsigned short* __restrict__ rankA,
                                                    const unsigned int* __restrict__ scannedA,
                                                    uint2* __restrict__ ebuf) {
  int i = blockIdx.x * 256 + threadIdx.x;  // exact grid == TE_TOT
  int t = i / E_EDGES;
  int e = i - t * E_EDGES;
  int b = e / EPB;
  int src = ei[t * 2 * E_EDGES + e];
  int dst = ei[(t * 2 + 1) * E_EDGES + e];
  float w = ew[i];
  int bkt = dst >> 8;
  unsigned int pos = scannedA[(t * NBKT + bkt) * BPT + b] + rankA[i];
  ebuf[pos] = make_uint2(((unsigned int)(dst & 255) << 16) | (unsigned int)src,
                         __float_as_uint(w));
}

// ---------------- pass B1: per-bucket cnt+deg, dinv, row_off, cursors ----------
__global__ __launch_bounds__(256) void k_bucket1(const uint2* __restrict__ ebuf,
                                                 const unsigned int* __restrict__ scannedA,
                                                 unsigned int* __restrict__ localscan,
                                                 float* __restrict__ dinv,
                                                 int* __restrict__ row_off) {
  __shared__ unsigned int cnt[256];
  __shared__ float degs[256];
  __shared__ unsigned int sc[256];
  const int tid = threadIdx.x, blk = blockIdx.x;  // blk = t*NBKT + bkt
  const int t = blk / NBKT, bkt = blk - t * NBKT;
  const unsigned int base = scannedA[blk * BPT];
  const unsigned int end = (blk == NBUCK_T - 1) ? (unsigned int)TE_TOT
                                                : scannedA[(blk + 1) * BPT];
  cnt[tid] = 0;
  degs[tid] = 0.f;
  __syncthreads();
  for (unsigned int i = base + tid; i < end; i += 256) {
    uint2 v = ebuf[i];
    unsigned int dlo = v.x >> 16;
    atomicAdd(&cnt[dlo], 1u);
    atomicAdd(&degs[dlo], __uint_as_float(v.y));
  }
  __syncthreads();
  unsigned int myc = cnt[tid];
  sc[tid] = myc;
  __syncthreads();
  for (int off = 1; off < 256; off <<= 1) {
    unsigned int a = (tid >= off) ? sc[tid - off] : 0;
    __syncthreads();
    sc[tid] += a;
    __syncthreads();
  }
  unsigned int start = base + (sc[tid] - myc);
  localscan[blk * 256 + tid] = start;
  int dst = bkt * 256 + tid;
  if (dst < N_NODES) {
    int tn = t * N_NODES + dst;
    dinv[tn] = rsqrtf(1.0f + degs[tid]);
    row_off[tn] = (int)start;
  }
  if (blk == NBUCK_T - 1 && tid == 0) row_off[M_TOT] = TE_TOT;
}

// ---------------- pass B2: in-place regroup to final CSR + fold dinv[src] ------
__global__ __launch_bounds__(256) void k_bucket2(uint2* __restrict__ ebuf,
                                                 const unsigned int* __restrict__ scannedA,
                                                 const unsigned int* __restrict__ localscan,
                                                 const float* __restrict__ dinv) {
  __shared__ uint2 stage[BKT_CAP];
  __shared__ unsigned int cursor[256];
  const int tid = threadIdx.x, blk = blockIdx.x;
  const int t = blk / NBKT;
  const unsigned int base = scannedA[blk * BPT];
  const unsigned int end = (blk == NBUCK_T - 1) ? (unsigned int)TE_TOT
                                                : scannedA[(blk + 1) * BPT];
  cursor[tid] = localscan[blk * 256 + tid];
  const unsigned int n = end - base;
  for (unsigned int j = tid; j < n; j += 256) stage[j] = ebuf[base + j];
  __syncthreads();
  const float* dv = dinv + t * N_NODES;
  for (unsigned int j = tid; j < n; j += 256) {
    uint2 v = stage[j];
    unsigned int dlo = v.x >> 16;
    unsigned int src = v.x & 0xFFFFu;
    unsigned int slot = atomicAdd(&cursor[dlo], 1u);
    float norm = __uint_as_float(v.y) * dv[src];
    ebuf[slot] = make_uint2(src, __float_as_uint(norm));
  }
}

// ---------------- layer-1 gather + ReLU + fused h1@W2 ----------------
// out_row = dvn*(sum_e norm_e*h[src_e] + dvn*h[n]) + b   (norm = w*dinv_src)
__global__ __launch_bounds__(256) void k_gather1(
    const float* __restrict__ h0, const float* __restrict__ dinv,
    const int* __restrict__ row_off, const uint2* __restrict__ csr,
    const float* __restrict__ W2, const float* __restrict__ b1,
    float* __restrict__ g) {
  __shared__ float h1s[16 * 65];
  __shared__ float w2s[64 * 32];
  const int tid = threadIdx.x;
#pragma unroll
  for (int r = 0; r < 2; ++r)
    ((float4*)w2s)[tid + r * 256] = ((const float4*)W2)[tid + r * 256];

  const int grp = tid >> 4;
  const int lane = tid & 15;
  const int tn = blockIdx.x * 16 + grp;
  const int t = tn / N_NODES;
  const int n = tn - t * N_NODES;
  const float dvn = dinv[tn];
  const float4* h04 = (const float4*)h0;
  float4 bv = ((const float4*)b1)[lane];

  float4 acc = h04[n * 16 + lane];
  acc.x *= dvn; acc.y *= dvn; acc.z *= dvn; acc.w *= dvn;

  int e0 = row_off[tn], e1 = row_off[tn + 1];
  for (int e = e0; e < e1; ++e) {
    uint2 v = csr[e];
    float norm = __uint_as_float(v.y);
    float4 hv = h04[v.x * 16 + lane];
    acc.x += norm * hv.x; acc.y += norm * hv.y;
    acc.z += norm * hv.z; acc.w += norm * hv.w;
  }
  int hb = grp * 65 + lane * 4;
  h1s[hb + 0] = fmaxf(acc.x * dvn + bv.x, 0.f);
  h1s[hb + 1] = fmaxf(acc.y * dvn + bv.y, 0.f);
  h1s[hb + 2] = fmaxf(acc.z * dvn + bv.z, 0.f);
  h1s[hb + 3] = fmaxf(acc.w * dvn + bv.w, 0.f);
  __syncthreads();

  const int n1 = tid >> 5;
  const int j = tid & 31;
  float a0 = 0.f, a1 = 0.f;
#pragma unroll 8
  for (int k = 0; k < 64; ++k) {
    float wv = w2s[k * 32 + j];
    a0 += h1s[n1 * 65 + k] * wv;
    a1 += h1s[(n1 + 8) * 65 + k] * wv;
  }
  const int tnb = blockIdx.x * 16;
  g[(size_t)(tnb + n1) * 32 + j] = a0;
  g[(size_t)(tnb + n1 + 8) * 32 + j] = a1;
}

// ---------------- layer-2 gather + bias + tanh -> out ----------------
__global__ __launch_bounds__(256) void k_gather2(
    const float* __restrict__ g, const float* __restrict__ dinv,
    const int* __restrict__ row_off, const uint2* __restrict__ csr,
    const float* __restrict__ b2, float* __restrict__ out) {
  const int tid = threadIdx.x;
  const int grp = tid >> 3;
  const int lane = tid & 7;
  const int tn = blockIdx.x * 32 + grp;
  const int t = tn / N_NODES;
  const int tbase = t * N_NODES;
  const float dvn = dinv[tn];
  const float4* g4 = (const float4*)g;
  float4 bv = ((const float4*)b2)[lane];

  float4 acc = g4[(size_t)tn * 8 + lane];
  acc.x *= dvn; acc.y *= dvn; acc.z *= dvn; acc.w *= dvn;

  int e0 = row_off[tn], e1 = row_off[tn + 1];
  for (int e = e0; e < e1; ++e) {
    uint2 v = csr[e];
    float norm = __uint_as_float(v.y);
    float4 gv = g4[(size_t)(tbase + (int)v.x) * 8 + lane];
    acc.x += norm * gv.x; acc.y += norm * gv.y;
    acc.z += norm * gv.z; acc.w += norm * gv.w;
  }
  float4 z;
  z.x = tanhf(acc.x * dvn + bv.x);
  z.y = tanhf(acc.y * dvn + bv.y);
  z.z = tanhf(acc.z * dvn + bv.z);
  z.w = tanhf(acc.w * dvn + bv.w);
  ((float4*)out)[(size_t)tn * 8 + lane] = z;
}

extern "C" void kernel_launch(void* const* d_in, const int* in_sizes, int n_in,
                              void* d_out, int out_size, void* d_ws, size_t ws_size,
                              hipStream_t stream) {
  const float* x = (const float*)d_in[0];
  const int* ei = (const int*)d_in[1];
  const float* ew = (const float*)d_in[2];
  const float* W1 = (const float*)d_in[3];
  const float* b1 = (const float*)d_in[4];
  const float* W2 = (const float*)d_in[5];
  const float* b2 = (const float*)d_in[6];
  float* out = (float*)d_out;

  char* base = (char*)d_ws;
  size_t o = 0;
  auto alloc = [&](size_t bytes) -> char* {
    char* r = base + o;
    o = (o + bytes + 255) & ~(size_t)255;
    return r;
  };
  float* h0 = (float*)alloc((size_t)N_NODES * HD * 4);               // 12.8 MB
  float* dinv = (float*)alloc((size_t)M_TOT * 4);                    // 1.6 MB
  int* row_off = (int*)alloc((size_t)(M_TOT + 1) * 4);               // 1.6 MB
  unsigned int* localscan = (unsigned int*)alloc((size_t)NBUCK_T * 256 * 4);  // 1.6 MB
  unsigned int* cntA = (unsigned int*)alloc((size_t)CNTA_LEN * 4);   // 0.78 MB
  unsigned int* scannedA = (unsigned int*)alloc((size_t)CNTA_LEN * 4);
  int* bsum = (int*)alloc(1024);
  int* bpre = (int*)alloc(1024);
  uint2* ebuf = (uint2*)alloc((size_t)TE_TOT * 8);                   // 51.2 MB
  float* g = (float*)alloc((size_t)M_TOT * ZD * 4);                  // 51.2 MB
  // rankA aliases start of g: dead after k_binscatter, before k_gather1 writes g
  unsigned short* rankA = (unsigned short*)g;                        // 12.8 MB
  // total ~122.6 MB; no memsets needed (everything fully written before read)

  k_h0<<<(N_NODES + 255) / 256, 256, 0, stream>>>(x, W1, h0);
  k_binhist<<<NBLK_A, 256, 0, stream>>>(ei, rankA, cntA);
  k_scan1<<<SCANA_NB, 256, 0, stream>>>(cntA, bsum);
  k_scan2<<<1, 256, 0, stream>>>(bsum, bpre);
  k_scan3<<<SCANA_NB, 256, 0, stream>>>(cntA, bpre, scannedA);
  k_binscatter<<<TE_TOT / 256, 256, 0, stream>>>(ei, ew, rankA, scannedA, ebuf);
  k_bucket1<<<NBUCK_T, 256, 0, stream>>>(ebuf, scannedA, localscan, dinv, row_off);
  k_bucket2<<<NBUCK_T, 256, 0, stream>>>(ebuf, scannedA, localscan, dinv);
  k_gather1<<<M_TOT / 16, 256, 0, stream>>>(h0, dinv, row_off, ebuf, W2, b1, g);
  k_gather2<<<M_TOT / 32, 256, 0, stream>>>(g, dinv, row_off, ebuf, b2, out);
}

// Round 4
// 590.708 us; speedup vs baseline: 2.6477x; 1.3340x over previous
//
#include <hip/hip_runtime.h>
#include <hip/hip_fp16.h>
#include <math.h>

#define N_NODES 50000
#define T_STEPS 8
#define E_EDGES 800000
#define XD 128
#define HD 64
#define ZD 32
#define M_TOT (T_STEPS * N_NODES)   // 400000
#define TE_TOT (T_STEPS * E_EDGES)  // 6400000

#define NBKT 196                    // ceil(50000/256) buckets of 256 dst values
#define BPT 125                     // pass-A blocks per timestep
#define EPB 6400                    // edges per pass-A block (125*6400 = 800000)
#define NBLK_A (T_STEPS * BPT)      // 1000
#define CNTA_LEN (T_STEPS * NBKT * BPT)  // 196000
#define NBUCK_T (T_STEPS * NBKT)    // 1568
#define BKT_CAP 4864                // mean 4096 + 12 sigma

#define SCAN_CH 2048
#define SCANA_NB ((CNTA_LEN + SCAN_CH - 1) / SCAN_CH)  // 96

__device__ __forceinline__ float4 h4tof4(ushort4 u) {
  return make_float4(__half2float(__ushort_as_half(u.x)),
                     __half2float(__ushort_as_half(u.y)),
                     __half2float(__ushort_as_half(u.z)),
                     __half2float(__ushort_as_half(u.w)));
}
__device__ __forceinline__ float cnorm(unsigned int c) {
  return __half2float(__ushort_as_half((unsigned short)(c >> 16)));
}

// ---------------- h0 = x @ W1  ([N,128] x [128,64]) -> fp16 ----------------
__global__ __launch_bounds__(256) void k_h0(const float* __restrict__ x,
                                            const float* __restrict__ W1,
                                            unsigned short* __restrict__ h0h) {
  __shared__ float xs[256 * 33];
  __shared__ float w1s[32 * 64];
  const int tid = threadIdx.x;
  const int nb = blockIdx.x * 256;
  const int nl_base = tid & 63;
  const int jg = tid >> 6;
  const float4* x4 = (const float4*)x;
  const float4* W14 = (const float4*)W1;

  float acc[4][16];
#pragma unroll
  for (int i = 0; i < 4; ++i)
#pragma unroll
    for (int j = 0; j < 16; ++j) acc[i][j] = 0.f;

  for (int kc = 0; kc < 4; ++kc) {
#pragma unroll
    for (int r = 0; r < 8; ++r) {
      int f4 = tid + r * 256;
      int nl = f4 >> 3;
      int k4 = f4 & 7;
      float4 v = make_float4(0.f, 0.f, 0.f, 0.f);
      int node = nb + nl;
      if (node < N_NODES) v = x4[node * 32 + kc * 8 + k4];
      int base = nl * 33 + k4 * 4;
      xs[base + 0] = v.x; xs[base + 1] = v.y;
      xs[base + 2] = v.z; xs[base + 3] = v.w;
    }
#pragma unroll
    for (int r = 0; r < 2; ++r) {
      int f4 = tid + r * 256;
      ((float4*)w1s)[f4] = W14[kc * 512 + f4];
    }
    __syncthreads();
#pragma unroll 4
    for (int k = 0; k < 32; ++k) {
      float xv[4];
#pragma unroll
      for (int i = 0; i < 4; ++i) xv[i] = xs[(nl_base + i * 64) * 33 + k];
      const float* wr = &w1s[k * 64 + jg * 16];
      float4 w0 = *(const float4*)(wr + 0);
      float4 w1v = *(const float4*)(wr + 4);
      float4 w2v = *(const float4*)(wr + 8);
      float4 w3v = *(const float4*)(wr + 12);
#pragma unroll
      for (int i = 0; i < 4; ++i) {
        acc[i][0] += xv[i] * w0.x;  acc[i][1] += xv[i] * w0.y;
        acc[i][2] += xv[i] * w0.z;  acc[i][3] += xv[i] * w0.w;
        acc[i][4] += xv[i] * w1v.x; acc[i][5] += xv[i] * w1v.y;
        acc[i][6] += xv[i] * w1v.z; acc[i][7] += xv[i] * w1v.w;
        acc[i][8] += xv[i] * w2v.x; acc[i][9] += xv[i] * w2v.y;
        acc[i][10] += xv[i] * w2v.z; acc[i][11] += xv[i] * w2v.w;
        acc[i][12] += xv[i] * w3v.x; acc[i][13] += xv[i] * w3v.y;
        acc[i][14] += xv[i] * w3v.z; acc[i][15] += xv[i] * w3v.w;
      }
    }
    __syncthreads();
  }
  ushort4* h4p = (ushort4*)h0h;
#pragma unroll
  for (int i = 0; i < 4; ++i) {
    int node = nb + nl_base + i * 64;
    if (node < N_NODES) {
#pragma unroll
      for (int q = 0; q < 4; ++q) {
        ushort4 s;
        s.x = __half_as_ushort(__float2half(acc[i][q * 4 + 0]));
        s.y = __half_as_ushort(__float2half(acc[i][q * 4 + 1]));
        s.z = __half_as_ushort(__float2half(acc[i][q * 4 + 2]));
        s.w = __half_as_ushort(__float2half(acc[i][q * 4 + 3]));
        h4p[(size_t)node * 16 + jg * 4 + q] = s;
      }
    }
  }
}

// ---------------- pass A: per-block LDS histogram over dst>>8 ----------------
__global__ __launch_bounds__(256) void k_binhist(const int* __restrict__ ei,
                                                 unsigned short* __restrict__ rankA,
                                                 unsigned int* __restrict__ cntA) {
  __shared__ unsigned int hist[NBKT];
  const int tid = threadIdx.x, bid = blockIdx.x;
  const int t = bid / BPT, b = bid - t * BPT;
  if (tid < NBKT) hist[tid] = 0;
  __syncthreads();
  const int* dstp = ei + (t * 2 + 1) * E_EDGES + b * EPB;
  const int gbase = t * E_EDGES + b * EPB;
#pragma unroll
  for (int it = 0; it < EPB / 256; ++it) {
    int e = it * 256 + tid;
    int dst = dstp[e];
    unsigned int r = atomicAdd(&hist[dst >> 8], 1u);
    rankA[gbase + e] = (unsigned short)r;
  }
  __syncthreads();
  if (tid < NBKT) cntA[(t * NBKT + tid) * BPT + b] = hist[tid];
}

// ---------------- hierarchical exclusive scan over cntA ----------------
__global__ __launch_bounds__(256) void k_scan1(const unsigned int* __restrict__ cntA,
                                               int* __restrict__ bsum) {
  __shared__ int s[256];
  int bid = blockIdx.x, tid = threadIdx.x;
  int base = bid * SCAN_CH;
  int v = 0;
#pragma unroll
  for (int r = 0; r < 8; ++r) {
    int i = base + tid + r * 256;
    if (i < CNTA_LEN) v += (int)cntA[i];
  }
  s[tid] = v;
  __syncthreads();
  for (int off = 128; off > 0; off >>= 1) {
    if (tid < off) s[tid] += s[tid + off];
    __syncthreads();
  }
  if (tid == 0) bsum[bid] = s[0];
}

__global__ __launch_bounds__(256) void k_scan2(const int* __restrict__ bsum,
                                               int* __restrict__ bpre) {
  __shared__ int s[256];
  int tid = threadIdx.x;
  int v = (tid < SCANA_NB) ? bsum[tid] : 0;
  s[tid] = v;
  __syncthreads();
  for (int off = 1; off < 256; off <<= 1) {
    int t = (tid >= off) ? s[tid - off] : 0;
    __syncthreads();
    s[tid] += t;
    __syncthreads();
  }
  bpre[tid] = s[tid] - v;
}

__global__ __launch_bounds__(256) void k_scan3(const unsigned int* __restrict__ cntA,
                                               const int* __restrict__ bpre,
                                               unsigned int* __restrict__ scannedA) {
  __shared__ int s[256];
  int bid = blockIdx.x, tid = threadIdx.x;
  int i0 = bid * SCAN_CH + tid * 8;
  int c[8];
  int lsum = 0;
#pragma unroll
  for (int j = 0; j < 8; ++j) {
    int i = i0 + j;
    c[j] = (i < CNTA_LEN) ? (int)cntA[i] : 0;
    lsum += c[j];
  }
  int v = lsum;
  s[tid] = v;
  __syncthreads();
  for (int off = 1; off < 256; off <<= 1) {
    int t = (tid >= off) ? s[tid - off] : 0;
    __syncthreads();
    s[tid] += t;
    __syncthreads();
  }
  int run = bpre[bid] + (s[tid] - v);
#pragma unroll
  for (int j = 0; j < 8; ++j) {
    int i = i0 + j;
    if (i < CNTA_LEN) {
      scannedA[i] = (unsigned int)run;
      run += c[j];
    }
  }
}

// ---------------- pass A scatter into bucket-grouped buffer ----------------
__global__ __launch_bounds__(256) void k_binscatter(const int* __restrict__ ei,
                                                    const float* __restrict__ ew,
                                                    const unsigned short* __restrict__ rankA,
                                                    const unsigned int* __restrict__ scannedA,
                                                    uint2* __restrict__ ebuf) {
  int i = blockIdx.x * 256 + threadIdx.x;
  int t = i / E_EDGES;
  int e = i - t * E_EDGES;
  int b = e / EPB;
  int src = ei[t * 2 * E_EDGES + e];
  int dst = ei[(t * 2 + 1) * E_EDGES + e];
  float w = ew[i];
  int bkt = dst >> 8;
  unsigned int pos = scannedA[(t * NBKT + bkt) * BPT + b] + rankA[i];
  ebuf[pos] = make_uint2(((unsigned int)(dst & 255) << 16) | (unsigned int)src,
                         __float_as_uint(w));
}

// ---------------- pass B1: per-bucket cnt+deg, dinv, row_off ----------------
__global__ __launch_bounds__(256) void k_bucket1(const uint2* __restrict__ ebuf,
                                                 const unsigned int* __restrict__ scannedA,
                                                 unsigned int* __restrict__ localscan,
                                                 float* __restrict__ dinv,
                                                 int* __restrict__ row_off) {
  __shared__ unsigned int cnt[256];
  __shared__ float degs[256];
  __shared__ unsigned int sc[256];
  const int tid = threadIdx.x, blk = blockIdx.x;
  const int t = blk / NBKT, bkt = blk - t * NBKT;
  const unsigned int base = scannedA[blk * BPT];
  const unsigned int end = (blk == NBUCK_T - 1) ? (unsigned int)TE_TOT
                                                : scannedA[(blk + 1) * BPT];
  cnt[tid] = 0;
  degs[tid] = 0.f;
  __syncthreads();
  for (unsigned int i = base + tid; i < end; i += 256) {
    uint2 v = ebuf[i];
    unsigned int dlo = v.x >> 16;
    atomicAdd(&cnt[dlo], 1u);
    atomicAdd(&degs[dlo], __uint_as_float(v.y));
  }
  __syncthreads();
  unsigned int myc = cnt[tid];
  sc[tid] = myc;
  __syncthreads();
  for (int off = 1; off < 256; off <<= 1) {
    unsigned int a = (tid >= off) ? sc[tid - off] : 0;
    __syncthreads();
    sc[tid] += a;
    __syncthreads();
  }
  unsigned int start = base + (sc[tid] - myc);
  localscan[blk * 256 + tid] = start;
  int dst = bkt * 256 + tid;
  if (dst < N_NODES) {
    int tn = t * N_NODES + dst;
    dinv[tn] = rsqrtf(1.0f + degs[tid]);
    row_off[tn] = (int)start;
  }
  if (blk == NBUCK_T - 1 && tid == 0) row_off[M_TOT] = TE_TOT;
}

// ------ pass B2: regroup to final packed u32 CSR (src | half(w*dinv_src)<<16) ------
__global__ __launch_bounds__(256) void k_bucket2(const uint2* __restrict__ ebuf,
                                                 const unsigned int* __restrict__ scannedA,
                                                 const unsigned int* __restrict__ localscan,
                                                 const float* __restrict__ dinv,
                                                 unsigned int* __restrict__ csr32) {
  __shared__ uint2 stage[BKT_CAP];
  __shared__ unsigned int cursor[256];
  const int tid = threadIdx.x, blk = blockIdx.x;
  const int t = blk / NBKT;
  const unsigned int base = scannedA[blk * BPT];
  const unsigned int end = (blk == NBUCK_T - 1) ? (unsigned int)TE_TOT
                                                : scannedA[(blk + 1) * BPT];
  cursor[tid] = localscan[blk * 256 + tid];
  const unsigned int n = end - base;
  for (unsigned int j = tid; j < n; j += 256) stage[j] = ebuf[base + j];
  __syncthreads();
  const float* dv = dinv + t * N_NODES;
  for (unsigned int j = tid; j < n; j += 256) {
    uint2 v = stage[j];
    unsigned int dlo = v.x >> 16;
    unsigned int src = v.x & 0xFFFFu;
    unsigned int slot = atomicAdd(&cursor[dlo], 1u);
    float norm = __uint_as_float(v.y) * dv[src];
    csr32[slot] = src | ((unsigned int)__half_as_ushort(__float2half(norm)) << 16);
  }
}

// ---------------- layer-1 gather (fp16 h0) + ReLU + fused h1@W2 -> fp16 g ------
__global__ __launch_bounds__(256) void k_gather1(
    const unsigned short* __restrict__ h0h, const float* __restrict__ dinv,
    const int* __restrict__ row_off, const unsigned int* __restrict__ csr,
    const float* __restrict__ W2, const float* __restrict__ b1,
    unsigned short* __restrict__ g16) {
  __shared__ float h1s[16 * 65];
  __shared__ float w2s[64 * 32];
  const int tid = threadIdx.x;
#pragma unroll
  for (int r = 0; r < 2; ++r)
    ((float4*)w2s)[tid + r * 256] = ((const float4*)W2)[tid + r * 256];

  const int grp = tid >> 4;
  const int lane = tid & 15;
  const int tn = blockIdx.x * 16 + grp;
  const int t = tn / N_NODES;
  const int n = tn - t * N_NODES;
  const float dvn = dinv[tn];
  const ushort4* h4 = (const ushort4*)h0h;
  float4 bv = ((const float4*)b1)[lane];

  float4 acc = h4tof4(h4[(size_t)n * 16 + lane]);
  acc.x *= dvn; acc.y *= dvn; acc.z *= dvn; acc.w *= dvn;

  const int e0 = row_off[tn], e1 = row_off[tn + 1];
  int e = e0;
  for (; e + 4 <= e1; e += 4) {
    unsigned int c0 = csr[e + 0], c1 = csr[e + 1];
    unsigned int c2 = csr[e + 2], c3 = csr[e + 3];
    ushort4 u0 = h4[(size_t)(c0 & 0xFFFFu) * 16 + lane];
    ushort4 u1 = h4[(size_t)(c1 & 0xFFFFu) * 16 + lane];
    ushort4 u2 = h4[(size_t)(c2 & 0xFFFFu) * 16 + lane];
    ushort4 u3 = h4[(size_t)(c3 & 0xFFFFu) * 16 + lane];
    float n0 = cnorm(c0), n1 = cnorm(c1), n2 = cnorm(c2), n3 = cnorm(c3);
    float4 f0 = h4tof4(u0), f1 = h4tof4(u1), f2 = h4tof4(u2), f3 = h4tof4(u3);
    acc.x += n0 * f0.x + n1 * f1.x + n2 * f2.x + n3 * f3.x;
    acc.y += n0 * f0.y + n1 * f1.y + n2 * f2.y + n3 * f3.y;
    acc.z += n0 * f0.z + n1 * f1.z + n2 * f2.z + n3 * f3.z;
    acc.w += n0 * f0.w + n1 * f1.w + n2 * f2.w + n3 * f3.w;
  }
  for (; e < e1; ++e) {
    unsigned int c = csr[e];
    ushort4 u = h4[(size_t)(c & 0xFFFFu) * 16 + lane];
    float nn = cnorm(c);
    float4 f = h4tof4(u);
    acc.x += nn * f.x; acc.y += nn * f.y;
    acc.z += nn * f.z; acc.w += nn * f.w;
  }
  int hb = grp * 65 + lane * 4;
  h1s[hb + 0] = fmaxf(acc.x * dvn + bv.x, 0.f);
  h1s[hb + 1] = fmaxf(acc.y * dvn + bv.y, 0.f);
  h1s[hb + 2] = fmaxf(acc.z * dvn + bv.z, 0.f);
  h1s[hb + 3] = fmaxf(acc.w * dvn + bv.w, 0.f);
  __syncthreads();

  const int n1i = tid >> 5;
  const int j = tid & 31;
  float a0 = 0.f, a1 = 0.f;
#pragma unroll 8
  for (int k = 0; k < 64; ++k) {
    float wv = w2s[k * 32 + j];
    a0 += h1s[n1i * 65 + k] * wv;
    a1 += h1s[(n1i + 8) * 65 + k] * wv;
  }
  const int tnb = blockIdx.x * 16;
  g16[(size_t)(tnb + n1i) * 32 + j] = __half_as_ushort(__float2half(a0));
  g16[(size_t)(tnb + n1i + 8) * 32 + j] = __half_as_ushort(__float2half(a1));
}

// ---------------- layer-2 gather (fp16 g) + bias + tanh -> out ----------------
__global__ __launch_bounds__(256) void k_gather2(
    const unsigned short* __restrict__ g16, const float* __restrict__ dinv,
    const int* __restrict__ row_off, const unsigned int* __restrict__ csr,
    const float* __restrict__ b2, float* __restrict__ out) {
  // bijective XCD-chunked swizzle: each XCD gets ~1 timestep's contiguous nodes
  // -> its 3.2MB fp16 g-slice is L2-resident (4MB/XCD)
  const int nwg = gridDim.x;
  const int orig = blockIdx.x;
  const int xcd = orig & 7, lid = orig >> 3;
  const int q = nwg >> 3, r = nwg & 7;
  const int bid = (xcd < r ? xcd * (q + 1) : r * (q + 1) + (xcd - r) * q) + lid;

  const int tid = threadIdx.x;
  const int grp = tid >> 3;
  const int lane = tid & 7;
  const int tn = bid * 32 + grp;
  const int t = tn / N_NODES;
  const int tbase = t * N_NODES;
  const float dvn = dinv[tn];
  const ushort4* g4 = (const ushort4*)g16;
  float4 bv = ((const float4*)b2)[lane];

  float4 acc = h4tof4(g4[(size_t)tn * 8 + lane]);
  acc.x *= dvn; acc.y *= dvn; acc.z *= dvn; acc.w *= dvn;

  const int e0 = row_off[tn], e1 = row_off[tn + 1];
  int e = e0;
  for (; e + 4 <= e1; e += 4) {
    unsigned int c0 = csr[e + 0], c1 = csr[e + 1];
    unsigned int c2 = csr[e + 2], c3 = csr[e + 3];
    ushort4 u0 = g4[(size_t)(tbase + (int)(c0 & 0xFFFFu)) * 8 + lane];
    ushort4 u1 = g4[(size_t)(tbase + (int)(c1 & 0xFFFFu)) * 8 + lane];
    ushort4 u2 = g4[(size_t)(tbase + (int)(c2 & 0xFFFFu)) * 8 + lane];
    ushort4 u3 = g4[(size_t)(tbase + (int)(c3 & 0xFFFFu)) * 8 + lane];
    float n0 = cnorm(c0), n1 = cnorm(c1), n2 = cnorm(c2), n3 = cnorm(c3);
    float4 f0 = h4tof4(u0), f1 = h4tof4(u1), f2 = h4tof4(u2), f3 = h4tof4(u3);
    acc.x += n0 * f0.x + n1 * f1.x + n2 * f2.x + n3 * f3.x;
    acc.y += n0 * f0.y + n1 * f1.y + n2 * f2.y + n3 * f3.y;
    acc.z += n0 * f0.z + n1 * f1.z + n2 * f2.z + n3 * f3.z;
    acc.w += n0 * f0.w + n1 * f1.w + n2 * f2.w + n3 * f3.w;
  }
  for (; e < e1; ++e) {
    unsigned int c = csr[e];
    ushort4 u = g4[(size_t)(tbase + (int)(c & 0xFFFFu)) * 8 + lane];
    float nn = cnorm(c);
    float4 f = h4tof4(u);
    acc.x += nn * f.x; acc.y += nn * f.y;
    acc.z += nn * f.z; acc.w += nn * f.w;
  }
  float4 z;
  z.x = tanhf(acc.x * dvn + bv.x);
  z.y = tanhf(acc.y * dvn + bv.y);
  z.z = tanhf(acc.z * dvn + bv.z);
  z.w = tanhf(acc.w * dvn + bv.w);
  ((float4*)out)[(size_t)tn * 8 + lane] = z;
}

extern "C" void kernel_launch(void* const* d_in, const int* in_sizes, int n_in,
                              void* d_out, int out_size, void* d_ws, size_t ws_size,
                              hipStream_t stream) {
  const float* x = (const float*)d_in[0];
  const int* ei = (const int*)d_in[1];
  const float* ew = (const float*)d_in[2];
  const float* W1 = (const float*)d_in[3];
  const float* b1 = (const float*)d_in[4];
  const float* W2 = (const float*)d_in[5];
  const float* b2 = (const float*)d_in[6];
  float* out = (float*)d_out;

  char* base = (char*)d_ws;
  size_t o = 0;
  auto alloc = [&](size_t bytes) -> char* {
    char* r = base + o;
    o = (o + bytes + 255) & ~(size_t)255;
    return r;
  };
  unsigned short* h0h = (unsigned short*)alloc((size_t)N_NODES * HD * 2);   // 6.4 MB
  float* dinv = (float*)alloc((size_t)M_TOT * 4);                           // 1.6 MB
  int* row_off = (int*)alloc((size_t)(M_TOT + 1) * 4);                      // 1.6 MB
  unsigned int* localscan = (unsigned int*)alloc((size_t)NBUCK_T * 256 * 4);// 1.6 MB
  unsigned int* cntA = (unsigned int*)alloc((size_t)CNTA_LEN * 4);          // 0.78 MB
  unsigned int* scannedA = (unsigned int*)alloc((size_t)CNTA_LEN * 4);
  int* bsum = (int*)alloc(1024);
  int* bpre = (int*)alloc(1024);
  uint2* ebuf = (uint2*)alloc((size_t)TE_TOT * 8);                          // 51.2 MB
  unsigned int* csr32 = (unsigned int*)alloc((size_t)TE_TOT * 4);           // 25.6 MB
  unsigned short* g16 = (unsigned short*)alloc((size_t)M_TOT * ZD * 2);     // 25.6 MB
  // rankA aliases g16: dead after k_binscatter, before k_gather1 writes g16
  unsigned short* rankA = (unsigned short*)g16;                             // 12.8 MB
  // total ~115 MB; no memsets needed (everything fully written before read)

  k_h0<<<(N_NODES + 255) / 256, 256, 0, stream>>>(x, W1, h0h);
  k_binhist<<<NBLK_A, 256, 0, stream>>>(ei, rankA, cntA);
  k_scan1<<<SCANA_NB, 256, 0, stream>>>(cntA, bsum);
  k_scan2<<<1, 256, 0, stream>>>(bsum, bpre);
  k_scan3<<<SCANA_NB, 256, 0, stream>>>(cntA, bpre, scannedA);
  k_binscatter<<<TE_TOT / 256, 256, 0, stream>>>(ei, ew, rankA, scannedA, ebuf);
  k_bucket1<<<NBUCK_T, 256, 0, stream>>>(ebuf, scannedA, localscan, dinv, row_off);
  k_bucket2<<<NBUCK_T, 256, 0, stream>>>(ebuf, scannedA, localscan, dinv, csr32);
  k_gather1<<<M_TOT / 16, 256, 0, stream>>>(h0h, dinv, row_off, csr32, W2, b1, g16);
  k_gather2<<<M_TOT / 32, 256, 0, stream>>>(g16, dinv, row_off, csr32, b2, out);
}